// Round 9
// baseline (314.571 us; speedup 1.0000x reference)
//
#include <hip/hip_runtime.h>
#include <stdint.h>
#include <type_traits>

// Problem constants
#define BB  4
#define SS  2048
#define DD  1024
#define HH  16
#define HDD 64

typedef __attribute__((ext_vector_type(8))) short s16x8;   // 8 bf16 (4 VGPRs)
typedef __attribute__((ext_vector_type(4))) float f32x4;   // MFMA C/D

__device__ inline short f2bf(float f) {
    union { float f; unsigned int u; } v; v.f = f;
    unsigned int r = (v.u + 0x7fffu + ((v.u >> 16) & 1u)) >> 16; // RNE
    return (short)r;
}

__device__ inline float bf2f(short s) {
    union { unsigned int u; float f; } v;
    v.u = ((unsigned int)(unsigned short)s) << 16;
    return v.f;
}

#define GLL(gp, lp) __builtin_amdgcn_global_load_lds( \
    (const __attribute__((address_space(1))) void*)(gp), \
    (__attribute__((address_space(3))) void*)(lp), 16, 0, 0)

// Raw barrier: orders this wave's LDS ops (lgkmcnt) then syncs. Does NOT
// drain vmcnt -> global_load_lds prefetch stays in flight across it.
__device__ inline void lds_barrier() {
    asm volatile("s_waitcnt lgkmcnt(0)" ::: "memory");
    __builtin_amdgcn_sched_barrier(0);
    __builtin_amdgcn_s_barrier();
    __builtin_amdgcn_sched_barrier(0);
}

// ---------------- fp32 -> bf16 cast (n % 8 == 0) ----------------
__global__ void cvt_kernel(const float* __restrict__ src, short* __restrict__ dst, int n) {
    int i = (blockIdx.x * 256 + threadIdx.x) * 8;
    if (i >= n) return;
    const float4* s = (const float4*)(src + i);
    float4 a = s[0], b = s[1];
    s16x8 o;
    o[0]=f2bf(a.x); o[1]=f2bf(a.y); o[2]=f2bf(a.z); o[3]=f2bf(a.w);
    o[4]=f2bf(b.x); o[5]=f2bf(b.y); o[6]=f2bf(b.z); o[7]=f2bf(b.w);
    *(s16x8*)(dst + i) = o;
}

// ---------------- GEMM C = A @ B^T + bias (BM=128 BN=128 BK=64, GLL dbuf) ----------
// (unchanged from round 8 - neutral vs m97 baseline; 2-phase ceiling noted)
template<int EPI>
__global__ __launch_bounds__(256, 2)
void gemm128(const short* __restrict__ A, const short* __restrict__ Bw,
             const float* __restrict__ bias, float* __restrict__ Cf,
             short* __restrict__ Qo, short* __restrict__ Ko, short* __restrict__ Vo,
             int M, int N, int K, int nbx)
{
    __shared__ short lsA[2][128 * 64];
    __shared__ short lsB[2][128 * 64];

    const int tid  = threadIdx.x;
    const int w    = tid >> 6, lane = tid & 63;
    const int quad = lane >> 4, l15 = lane & 15;
    const int wm = w >> 1, wn = w & 1;
    const int cpx = gridDim.x >> 3;
    const int swz = (blockIdx.x & 7) * cpx + (blockIdx.x >> 3);
    const int m0 = (swz / nbx) * 128, n0 = (swz % nbx) * 128;
    const int grow = lane >> 3;                 // row-within-octet this lane covers
    const int gcol = ((lane & 7) ^ grow) * 8;   // inverse-swizzled source col (shorts)
    const int l7 = l15 & 7;

    f32x4 acc[4][4] = {};

    auto issue = [&](int kt, int buf) {
#pragma unroll
        for (int jj = 0; jj < 4; ++jj) {        // A: 128 rows = 16 octets, 4/wave
            int row = w * 32 + jj * 8 + grow;
            GLL(A + (size_t)(m0 + row) * K + kt * 64 + gcol,
                &lsA[buf][(w * 4 + jj) * 512]);
        }
#pragma unroll
        for (int jj = 0; jj < 4; ++jj) {        // B: 128 rows = 16 octets, 4/wave
            int row = w * 32 + jj * 8 + grow;
            GLL(Bw + (size_t)(n0 + row) * K + kt * 64 + gcol,
                &lsB[buf][(w * 4 + jj) * 512]);
        }
    };

    const int NT = K >> 6;                      // BK=64 K-tiles
    issue(0, 0);
    for (int t = 0; t < NT; ++t) {
        const int buf = t & 1;
        lds_barrier();                          // A: all waves done reading buf^1
        if (t + 1 < NT) {
            issue(t + 1, buf ^ 1);
            asm volatile("s_waitcnt vmcnt(8)" ::: "memory");
        } else {
            asm volatile("s_waitcnt vmcnt(0)" ::: "memory");
        }
        __builtin_amdgcn_sched_barrier(0);
        __builtin_amdgcn_s_barrier();           // B: tile t fully staged (all waves)
        __builtin_amdgcn_sched_barrier(0);

        s16x8 af[4][2], bfr[4][2];
#pragma unroll
        for (int mf = 0; mf < 4; ++mf)
#pragma unroll
            for (int ks = 0; ks < 2; ++ks)
                af[mf][ks] = *(const s16x8*)&lsA[buf][(wm * 64 + mf * 16 + l15) * 64 +
                                                     (((ks * 4 + quad) ^ l7) * 8)];
#pragma unroll
        for (int nf = 0; nf < 4; ++nf)
#pragma unroll
            for (int ks = 0; ks < 2; ++ks)
                bfr[nf][ks] = *(const s16x8*)&lsB[buf][(wn * 64 + nf * 16 + l15) * 64 +
                                                      (((ks * 4 + quad) ^ l7) * 8)];

        __builtin_amdgcn_s_setprio(1);
#pragma unroll
        for (int ks = 0; ks < 2; ++ks)
#pragma unroll
            for (int mf = 0; mf < 4; ++mf)
#pragma unroll
                for (int nf = 0; nf < 4; ++nf)
                    acc[mf][nf] = __builtin_amdgcn_mfma_f32_16x16x32_bf16(
                                      af[mf][ks], bfr[nf][ks], acc[mf][nf], 0, 0, 0);
        __builtin_amdgcn_s_setprio(0);
    }

    if (EPI == 0) {
#pragma unroll
        for (int mf = 0; mf < 4; ++mf) {
            int row = m0 + wm * 64 + mf * 16 + quad * 4;
#pragma unroll
            for (int nf = 0; nf < 4; ++nf) {
                int col = n0 + wn * 64 + nf * 16 + l15;
                float bv = bias[col];
#pragma unroll
                for (int r = 0; r < 4; ++r)
                    Cf[(size_t)(row + r) * N + col] = acc[mf][nf][r] + bv;
            }
        }
    } else {
#pragma unroll
        for (int mf = 0; mf < 4; ++mf) {
            int row = m0 + wm * 64 + mf * 16 + quad * 4;
#pragma unroll
            for (int nf = 0; nf < 4; ++nf) {
                int col = n0 + wn * 64 + nf * 16 + l15;
                float bv = bias[col];
                int sel = col >> 10, h = (col >> 6) & 15, hd = col & 63;
#pragma unroll
                for (int r = 0; r < 4; ++r) {
                    int rr = row + r;
                    int b = rr >> 11, s = rr & 2047;
                    short val = f2bf(acc[mf][nf][r] + bv);
                    if (sel == 0)      Qo[(((size_t)b * HH + h) * SS + s) * HDD + hd] = val;
                    else if (sel == 1) Ko[(((size_t)b * HH + h) * SS + s) * HDD + hd] = val;
                    else               Vo[(((size_t)b * HH + h) * HDD + hd) * SS + s] = val;
                }
            }
        }
    }
}

// ---------------- causal flash attention (pipelined: QK(t+1) || softmax(t)) --------
// Q,K: (b,h,s,hd) bf16; V: (b,h,hd,s) bf16; O: (b,s,h*64+hd) bf16
// grid: (8, B*H) = 512 blocks, QBLK=128 (4 waves x 32 rows), KVBLK=64.
// Round-8 diagnosis: per-tile chain vmcnt->QK->softmax->PV fully serial; 40% of
// cycles neither pipe busy. This version breaks the chain:
//   - S is software-pipelined: QK(t+1) issues at iter t (after barrier B), its MFMA
//     latency hides under P-write+PV; softmax(t) never waits on fresh MFMA results.
//   - softmax(t) runs BEFORE the vmcnt wait -> overlaps the GLL flight time.
// Staging schedule: K(j)->lsK[j&1] issued at iter j-2; V(j)->lsV[j&1] at iter j-1.
// Per-iter vmcnt = #GLLs issued this iter (4 steady / 2 near-tail / 0 last), so the
// wait always targets loads issued a full iteration earlier. Barrier A (lgkm+sbar)
// gates buffer overwrite; barrier B makes staged data visible (vmcnt counted, T4).
// All layouts/swizzles identical to round 8 (0 bank conflicts measured).
__global__ __launch_bounds__(256, 2)
void attn_kernel(const short* __restrict__ Q, const short* __restrict__ Kb,
                 const short* __restrict__ Vb, const int* __restrict__ mask,
                 short* __restrict__ O)
{
    __shared__ short lsK[2][64 * 64];      // [buf][key][hd] linear (GLL), src-swizzled
    __shared__ short lsV[2][64 * 64];      // [buf][hd][key] linear (GLL), src-swizzled
    __shared__ short lsP[4][32 * 64];      // per-wave P [qrow 32][key 64], granule-XOR
    __shared__ short lsM[SS];              // mask additive, bf16 (0 or -1e30)

    const int tid  = threadIdx.x;
    const int w    = tid >> 6, lane = tid & 63;
    const int quad = lane >> 4, l15 = lane & 15;
    const int bx = blockIdx.x, bh = blockIdx.y;
    const int b = bh >> 4;
    const size_t baseQK = (size_t)bh * SS * HDD;
    const size_t baseV  = (size_t)bh * HDD * SS;
    const float SC = 0.18033688f;          // (1/8) * log2(e)
    const int grow = lane >> 3;            // GLL: row-within-8 covered by this lane
    const int gcol = ((lane & 7) ^ grow) * 8;  // GLL: inverse-swizzled source col (shorts)
    const int l7 = l15 & 7;

    // stage mask -> lsM once (visible after first lds_barrier)
    {
        const int4* mp = (const int4*)(mask + b * SS);
        int4 a = mp[tid * 2], c = mp[tid * 2 + 1];
        const short NEG = f2bf(-1e30f);
        s16x8 mo;
        mo[0] = a.x ? (short)0 : NEG; mo[1] = a.y ? (short)0 : NEG;
        mo[2] = a.z ? (short)0 : NEG; mo[3] = a.w ? (short)0 : NEG;
        mo[4] = c.x ? (short)0 : NEG; mo[5] = c.y ? (short)0 : NEG;
        mo[6] = c.z ? (short)0 : NEG; mo[7] = c.w ? (short)0 : NEG;
        *(s16x8*)&lsM[tid * 8] = mo;
    }

    auto issueK = [&](int kv0, int buf) {
#pragma unroll
        for (int jj = 0; jj < 2; ++jj) {
            int row = w * 16 + jj * 8 + grow;                  // key row
            GLL(Kb + baseQK + (size_t)(kv0 + row) * HDD + gcol,
                &lsK[buf][(w * 2 + jj) * 512]);
        }
    };
    auto issueV = [&](int kv0, int buf) {
#pragma unroll
        for (int jj = 0; jj < 2; ++jj) {
            int row = w * 16 + jj * 8 + grow;                  // hd row
            GLL(Vb + baseV + (size_t)row * SS + kv0 + gcol,
                &lsV[buf][(w * 2 + jj) * 512]);
        }
    };

    for (int t2 = 0; t2 < 2; ++t2) {
        const int qb = t2 ? bx : (15 - bx);  // heavy q-tile first
        const int q0 = qb * 128;
        const int qw0 = q0 + w * 32;         // this wave's first q-row

        s16x8 aq[2][2];
#pragma unroll
        for (int s = 0; s < 2; ++s)
#pragma unroll
            for (int ks = 0; ks < 2; ++ks)
                aq[s][ks] = *(const s16x8*)(Q + baseQK +
                    (size_t)(qw0 + s * 16 + l15) * HDD + ks * 32 + quad * 8);

        float m_r[2][4], l_r[2][4];
        f32x4 o_acc[2][4] = {};
#pragma unroll
        for (int s = 0; s < 2; ++s)
#pragma unroll
            for (int r = 0; r < 4; ++r) { m_r[s][r] = -1e30f; l_r[s][r] = 0.f; }

        const int n = 2 * qb + 2;            // 64-key tiles; last two are diagonal

        // QK MFMA block (raw scores; scale/mask applied later in softmax)
        auto qkt = [&](int kbuf, f32x4 (&svo)[2][4]) {
#pragma unroll
            for (int s = 0; s < 2; ++s)
#pragma unroll
                for (int nt = 0; nt < 4; ++nt) svo[s][nt] = f32x4{};
#pragma unroll
            for (int ks = 0; ks < 2; ++ks)
#pragma unroll
                for (int nt = 0; nt < 4; ++nt) {
                    s16x8 kf = *(const s16x8*)&lsK[kbuf][(nt * 16 + l15) * 64 +
                                                        (((ks * 4 + quad) ^ l7) * 8)];
#pragma unroll
                    for (int s = 0; s < 2; ++s)
                        svo[s][nt] = __builtin_amdgcn_mfma_f32_16x16x32_bf16(
                                         aq[s][ks], kf, svo[s][nt], 0, 0, 0);
                }
        };

        // ---- prologue: stage K(0),V(0),K(1); compute S(0) ----
        lds_barrier();                       // prev t2's reads done / mask visible
        issueK(0, 0); issueV(0, 0); issueK(64, 1);
        asm volatile("s_waitcnt vmcnt(2)" ::: "memory");   // K(0),V(0) landed; K(1) in flight
        __builtin_amdgcn_sched_barrier(0);
        __builtin_amdgcn_s_barrier();
        __builtin_amdgcn_sched_barrier(0);

        f32x4 sv[2][4];
        qkt(0, sv);                          // S(0) raw

        for (int t = 0; t < n; ++t) {
            const int buf = t & 1;
            lds_barrier();                   // A: frees lsK[buf] (K(t) dead), lsV[buf^1] (V(t-1) dead)
            if (t + 2 < n) issueK((t + 2) * 64, buf);
            if (t + 1 < n) issueV((t + 1) * 64, buf ^ 1);

            // ---- softmax(S(t)) : overlaps the GLL flight time ----
            const bool caus = (t >= n - 2);
            const int kv0 = t * 64;
            float madd[4];
#pragma unroll
            for (int nt = 0; nt < 4; ++nt)
                madd[nt] = bf2f(lsM[kv0 + nt * 16 + l15]);
#pragma unroll
            for (int s = 0; s < 2; ++s) {
                const int rowg0 = qw0 + s * 16 + quad * 4;
#pragma unroll
                for (int nt = 0; nt < 4; ++nt) {
                    int colg = kv0 + nt * 16 + l15;
#pragma unroll
                    for (int r = 0; r < 4; ++r) {
                        float scv = sv[s][nt][r] * SC + madd[nt];
                        if (caus && colg > rowg0 + r) scv = -1e30f;
                        sv[s][nt][r] = scv;
                    }
                }
            }
            // row max (16-lane groups), then T13 defer-max decision
            float rm[2][4];
#pragma unroll
            for (int s = 0; s < 2; ++s)
#pragma unroll
                for (int r = 0; r < 4; ++r) {
                    float v = fmaxf(fmaxf(sv[s][0][r], sv[s][1][r]),
                                    fmaxf(sv[s][2][r], sv[s][3][r]));
                    v = fmaxf(v, __shfl_xor(v, 1));
                    v = fmaxf(v, __shfl_xor(v, 2));
                    v = fmaxf(v, __shfl_xor(v, 4));
                    v = fmaxf(v, __shfl_xor(v, 8));
                    rm[s][r] = v;
                }
            float need = rm[0][0] - m_r[0][0];
#pragma unroll
            for (int s = 0; s < 2; ++s)
#pragma unroll
                for (int r = 0; r < 4; ++r)
                    need = fmaxf(need, rm[s][r] - m_r[s][r]);
            if (!__all(need <= 8.0f)) {      // rescale only when some row's max grew >8
#pragma unroll
                for (int s = 0; s < 2; ++s)
#pragma unroll
                    for (int r = 0; r < 4; ++r) {
                        float nm = fmaxf(m_r[s][r], rm[s][r]);
                        float al = __builtin_amdgcn_exp2f(m_r[s][r] - nm);
                        m_r[s][r] = nm;
                        l_r[s][r] *= al;
#pragma unroll
                        for (int ht = 0; ht < 4; ++ht)
                            o_acc[s][ht][r] *= al;
                    }
            }
            // P = exp2(S - m); per-lane partial l (sum-reduce deferred to epilogue)
#pragma unroll
            for (int s = 0; s < 2; ++s)
#pragma unroll
                for (int r = 0; r < 4; ++r) {
                    float rs = 0.f;
#pragma unroll
                    for (int nt = 0; nt < 4; ++nt) {
                        float p = __builtin_amdgcn_exp2f(sv[s][nt][r] - m_r[s][r]);
                        sv[s][nt][r] = p;
                        rs += p;
                    }
                    l_r[s][r] += rs;
                }

            // ---- counted vmcnt: K(t+1), V(t) (issued last iter) have landed ----
            __builtin_amdgcn_sched_barrier(0);
            if (t + 2 < n)      asm volatile("s_waitcnt vmcnt(4)" ::: "memory");
            else if (t + 1 < n) asm volatile("s_waitcnt vmcnt(2)" ::: "memory");
            else                asm volatile("s_waitcnt vmcnt(0)" ::: "memory");
            __builtin_amdgcn_sched_barrier(0);
            __builtin_amdgcn_s_barrier();    // B: staged data visible to all waves
            __builtin_amdgcn_sched_barrier(0);

            // ---- QK(t+1) in the MFMA shadow (result consumed next iter) ----
            f32x4 svn[2][4];
            if (t + 1 < n) qkt(buf ^ 1, svn);

            // ---- P(t) -> wave-private swizzled buffer ----
            short* lsPw = lsP[w];
#pragma unroll
            for (int s = 0; s < 2; ++s)
#pragma unroll
                for (int nt = 0; nt < 4; ++nt)
#pragma unroll
                    for (int r = 0; r < 4; ++r) {
                        int prow = s * 16 + quad * 4 + r;
                        lsPw[prow * 64 + (((nt * 2 + (l15 >> 3)) ^ (prow & 7)) << 3) + l7]
                            = f2bf(sv[s][nt][r]);
                    }
            asm volatile("s_waitcnt lgkmcnt(0)" ::: "memory");
            __builtin_amdgcn_sched_barrier(0);

            // ---- O += P(t) V(t) ----
            s16x8 ap[2][2];
#pragma unroll
            for (int s = 0; s < 2; ++s)
#pragma unroll
                for (int k2 = 0; k2 < 2; ++k2)
                    ap[s][k2] = *(const s16x8*)&lsPw[(s * 16 + l15) * 64 +
                                                     (((k2 * 4 + quad) ^ l7) << 3)];
#pragma unroll
            for (int ht = 0; ht < 4; ++ht)
#pragma unroll
                for (int k2 = 0; k2 < 2; ++k2) {
                    s16x8 vf = *(const s16x8*)&lsV[buf][(ht * 16 + l15) * 64 +
                                                        (((k2 * 4 + quad) ^ l7) * 8)];
#pragma unroll
                    for (int s = 0; s < 2; ++s)
                        o_acc[s][ht] = __builtin_amdgcn_mfma_f32_16x16x32_bf16(
                                           ap[s][k2], vf, o_acc[s][ht], 0, 0, 0);
                }

            // rotate pipelined S
            if (t + 1 < n) {
#pragma unroll
                for (int s = 0; s < 2; ++s)
#pragma unroll
                    for (int nt = 0; nt < 4; ++nt)
                        sv[s][nt] = svn[s][nt];
            }
        }

        // epilogue: reduce l over 16-lane groups, then O/l -> (b, s, h*64+hd) bf16
        const int hcol = (bh & 15) * HDD;
#pragma unroll
        for (int s = 0; s < 2; ++s)
#pragma unroll
            for (int r = 0; r < 4; ++r) {
                float ls = l_r[s][r];
                ls += __shfl_xor(ls, 1);
                ls += __shfl_xor(ls, 2);
                ls += __shfl_xor(ls, 4);
                ls += __shfl_xor(ls, 8);
                float inv = 1.0f / ls;
                int srow = qw0 + s * 16 + quad * 4 + r;
                size_t base = ((size_t)b * SS + srow) * DD + hcol;
#pragma unroll
                for (int ht = 0; ht < 4; ++ht)
                    O[base + ht * 16 + l15] = f2bf(o_acc[s][ht][r] * inv);
            }
    }
}

// ---------------- launch ----------------
extern "C" void kernel_launch(void* const* d_in, const int* in_sizes, int n_in,
                              void* d_out, int out_size, void* d_ws, size_t ws_size,
                              hipStream_t stream) {
    const float* x     = (const float*)d_in[0];
    const int*   mask  = (const int*)d_in[1];
    const float* qkv_w = (const float*)d_in[2];
    const float* qkv_b = (const float*)d_in[3];
    const float* out_w = (const float*)d_in[4];
    const float* out_b = (const float*)d_in[5];
    float* out = (float*)d_out;

    const size_t M1 = (size_t)BB * SS;       // 8192
    short* ws  = (short*)d_ws;
    short* xb  = ws;
    short* qwb = xb  + M1 * DD;
    short* owb = qwb + (size_t)3 * DD * DD;
    short* Qb  = owb + (size_t)DD * DD;
    short* Kb  = Qb  + M1 * DD;
    short* Vb  = Kb  + M1 * DD;
    short* Ob  = Vb  + M1 * DD;

    cvt_kernel<<<(int)(M1 * DD / 8 / 256), 256, 0, stream>>>(x, xb, (int)(M1 * DD));
    cvt_kernel<<<3 * DD * DD / 8 / 256, 256, 0, stream>>>(qkv_w, qwb, 3 * DD * DD);
    cvt_kernel<<<DD * DD / 8 / 256, 256, 0, stream>>>(out_w, owb, DD * DD);

    // qkv: M=8192, N=3072 -> 64 x 24 = 1536 blocks (2/CU x 3 exact rounds)
    gemm128<1><<<1536, 256, 0, stream>>>(xb, qwb, qkv_b, nullptr,
                                         Qb, Kb, Vb, 8192, 3072, 1024, 24);
    attn_kernel<<<dim3(8, BB * HH), 256, 0, stream>>>(Qb, Kb, Vb, mask, Ob);
    // out: M=8192, N=1024 -> 64 x 8 = 512 blocks (2/CU x 1 round)
    gemm128<0><<<512, 256, 0, stream>>>(Ob, owb, out_b, out,
                                        nullptr, nullptr, nullptr, 8192, 1024, 1024, 8);
}

// Round 10
// 292.060 us; speedup vs baseline: 1.0771x; 1.0771x over previous
//
#include <hip/hip_runtime.h>
#include <stdint.h>
#include <type_traits>

// Problem constants
#define BB  4
#define SS  2048
#define DD  1024
#define HH  16
#define HDD 64

typedef __attribute__((ext_vector_type(8))) short s16x8;   // 8 bf16 (4 VGPRs)
typedef __attribute__((ext_vector_type(4))) float f32x4;   // MFMA C/D

__device__ inline short f2bf(float f) {
    union { float f; unsigned int u; } v; v.f = f;
    unsigned int r = (v.u + 0x7fffu + ((v.u >> 16) & 1u)) >> 16; // RNE
    return (short)r;
}

__device__ inline float bf2f(short s) {
    union { unsigned int u; float f; } v;
    v.u = ((unsigned int)(unsigned short)s) << 16;
    return v.f;
}

__device__ inline unsigned int pk2(float a, float b) {
    return (unsigned int)(unsigned short)f2bf(a) |
           ((unsigned int)(unsigned short)f2bf(b) << 16);
}

#define GLL(gp, lp) __builtin_amdgcn_global_load_lds( \
    (const __attribute__((address_space(1))) void*)(gp), \
    (__attribute__((address_space(3))) void*)(lp), 16, 0, 0)

// Raw barrier: orders this wave's LDS ops (lgkmcnt) then syncs. Does NOT
// drain vmcnt -> global_load_lds prefetch stays in flight across it.
__device__ inline void lds_barrier() {
    asm volatile("s_waitcnt lgkmcnt(0)" ::: "memory");
    __builtin_amdgcn_sched_barrier(0);
    __builtin_amdgcn_s_barrier();
    __builtin_amdgcn_sched_barrier(0);
}

// ---------------- fp32 -> bf16 cast (n % 8 == 0) ----------------
__global__ void cvt_kernel(const float* __restrict__ src, short* __restrict__ dst, int n) {
    int i = (blockIdx.x * 256 + threadIdx.x) * 8;
    if (i >= n) return;
    const float4* s = (const float4*)(src + i);
    float4 a = s[0], b = s[1];
    s16x8 o;
    o[0]=f2bf(a.x); o[1]=f2bf(a.y); o[2]=f2bf(a.z); o[3]=f2bf(a.w);
    o[4]=f2bf(b.x); o[5]=f2bf(b.y); o[6]=f2bf(b.z); o[7]=f2bf(b.w);
    *(s16x8*)(dst + i) = o;
}

// ---------------- GEMM C = A @ B^T + bias (BM=128 BN=128 BK=64, GLL dbuf) ----------
// (unchanged from round 8)
template<int EPI>
__global__ __launch_bounds__(256, 2)
void gemm128(const short* __restrict__ A, const short* __restrict__ Bw,
             const float* __restrict__ bias, float* __restrict__ Cf,
             short* __restrict__ Qo, short* __restrict__ Ko, short* __restrict__ Vo,
             int M, int N, int K, int nbx)
{
    __shared__ short lsA[2][128 * 64];
    __shared__ short lsB[2][128 * 64];

    const int tid  = threadIdx.x;
    const int w    = tid >> 6, lane = tid & 63;
    const int quad = lane >> 4, l15 = lane & 15;
    const int wm = w >> 1, wn = w & 1;
    const int cpx = gridDim.x >> 3;
    const int swz = (blockIdx.x & 7) * cpx + (blockIdx.x >> 3);
    const int m0 = (swz / nbx) * 128, n0 = (swz % nbx) * 128;
    const int grow = lane >> 3;                 // row-within-octet this lane covers
    const int gcol = ((lane & 7) ^ grow) * 8;   // inverse-swizzled source col (shorts)
    const int l7 = l15 & 7;

    f32x4 acc[4][4] = {};

    auto issue = [&](int kt, int buf) {
#pragma unroll
        for (int jj = 0; jj < 4; ++jj) {        // A: 128 rows = 16 octets, 4/wave
            int row = w * 32 + jj * 8 + grow;
            GLL(A + (size_t)(m0 + row) * K + kt * 64 + gcol,
                &lsA[buf][(w * 4 + jj) * 512]);
        }
#pragma unroll
        for (int jj = 0; jj < 4; ++jj) {        // B: 128 rows = 16 octets, 4/wave
            int row = w * 32 + jj * 8 + grow;
            GLL(Bw + (size_t)(n0 + row) * K + kt * 64 + gcol,
                &lsB[buf][(w * 4 + jj) * 512]);
        }
    };

    const int NT = K >> 6;                      // BK=64 K-tiles
    issue(0, 0);
    for (int t = 0; t < NT; ++t) {
        const int buf = t & 1;
        lds_barrier();                          // A: all waves done reading buf^1
        if (t + 1 < NT) {
            issue(t + 1, buf ^ 1);
            asm volatile("s_waitcnt vmcnt(8)" ::: "memory");
        } else {
            asm volatile("s_waitcnt vmcnt(0)" ::: "memory");
        }
        __builtin_amdgcn_sched_barrier(0);
        __builtin_amdgcn_s_barrier();           // B: tile t fully staged (all waves)
        __builtin_amdgcn_sched_barrier(0);

        s16x8 af[4][2], bfr[4][2];
#pragma unroll
        for (int mf = 0; mf < 4; ++mf)
#pragma unroll
            for (int ks = 0; ks < 2; ++ks)
                af[mf][ks] = *(const s16x8*)&lsA[buf][(wm * 64 + mf * 16 + l15) * 64 +
                                                     (((ks * 4 + quad) ^ l7) * 8)];
#pragma unroll
        for (int nf = 0; nf < 4; ++nf)
#pragma unroll
            for (int ks = 0; ks < 2; ++ks)
                bfr[nf][ks] = *(const s16x8*)&lsB[buf][(wn * 64 + nf * 16 + l15) * 64 +
                                                      (((ks * 4 + quad) ^ l7) * 8)];

        __builtin_amdgcn_s_setprio(1);
#pragma unroll
        for (int ks = 0; ks < 2; ++ks)
#pragma unroll
            for (int mf = 0; mf < 4; ++mf)
#pragma unroll
                for (int nf = 0; nf < 4; ++nf)
                    acc[mf][nf] = __builtin_amdgcn_mfma_f32_16x16x32_bf16(
                                      af[mf][ks], bfr[nf][ks], acc[mf][nf], 0, 0, 0);
        __builtin_amdgcn_s_setprio(0);
    }

    if (EPI == 0) {
#pragma unroll
        for (int mf = 0; mf < 4; ++mf) {
            int row = m0 + wm * 64 + mf * 16 + quad * 4;
#pragma unroll
            for (int nf = 0; nf < 4; ++nf) {
                int col = n0 + wn * 64 + nf * 16 + l15;
                float bv = bias[col];
#pragma unroll
                for (int r = 0; r < 4; ++r)
                    Cf[(size_t)(row + r) * N + col] = acc[mf][nf][r] + bv;
            }
        }
    } else {
#pragma unroll
        for (int mf = 0; mf < 4; ++mf) {
            int row = m0 + wm * 64 + mf * 16 + quad * 4;
#pragma unroll
            for (int nf = 0; nf < 4; ++nf) {
                int col = n0 + wn * 64 + nf * 16 + l15;
                float bv = bias[col];
                int sel = col >> 10, h = (col >> 6) & 15, hd = col & 63;
#pragma unroll
                for (int r = 0; r < 4; ++r) {
                    int rr = row + r;
                    int b = rr >> 11, s = rr & 2047;
                    short val = f2bf(acc[mf][nf][r] + bv);
                    if (sel == 0)      Qo[(((size_t)b * HH + h) * SS + s) * HDD + hd] = val;
                    else if (sel == 1) Ko[(((size_t)b * HH + h) * SS + s) * HDD + hd] = val;
                    else               Vo[(((size_t)b * HH + h) * HDD + hd) * SS + s] = val;
                }
            }
        }
    }
}

// ---------------- causal flash attention (swapped QK^T, in-lane softmax) -----------
// Round-8 staging structure (proven: counted vmcnt, 0-conflict K/V swizzle) with the
// T12 swapped-QK rework: sv = mfma(K, Q) -> D[key][q], lane holds q=l15, key=quad*4+r.
// Softmax reduction over keys is IN-LANE (15 fmax) + 2 shfl_xor(16/32) instead of
// 4 shfl per row; m,l are per-s scalars. P (4 consecutive k per lane) packs to
// 2 u32 -> 8 ds_write_b64/tile (was 32 ds_write_u16). Consumer ap read unchanged
// (writer granule (nt*2+(quad>>1))^ (l15&7), half quad&1 == reader (k2*4+quad)^l7).
// DS-pipe ops/tile: ~116 -> ~32 (round-5 diagnosis: throughput-bound on VALU+DS).
__global__ __launch_bounds__(256, 2)
void attn_kernel(const short* __restrict__ Q, const short* __restrict__ Kb,
                 const short* __restrict__ Vb, const int* __restrict__ mask,
                 short* __restrict__ O)
{
    __shared__ short lsK[2][64 * 64];      // [buf][key][hd] linear (GLL), src-swizzled
    __shared__ short lsV[2][64 * 64];      // [buf][hd][key] linear (GLL), src-swizzled
    __shared__ short lsP[4][32 * 64];      // per-wave P [qrow 32][key 64], granule-XOR
    __shared__ short lsM[SS];              // mask additive, bf16 (0 or -1e30)

    const int tid  = threadIdx.x;
    const int w    = tid >> 6, lane = tid & 63;
    const int quad = lane >> 4, l15 = lane & 15;
    const int bx = blockIdx.x, bh = blockIdx.y;
    const int b = bh >> 4;
    const size_t baseQK = (size_t)bh * SS * HDD;
    const size_t baseV  = (size_t)bh * HDD * SS;
    const float SC = 0.18033688f;          // (1/8) * log2(e)
    const int grow = lane >> 3;            // GLL: row-within-8 covered by this lane
    const int gcol = ((lane & 7) ^ grow) * 8;  // GLL: inverse-swizzled source col (shorts)
    const int l7 = l15 & 7;

    // stage mask -> lsM once (visible after first lds_barrier)
    {
        const int4* mp = (const int4*)(mask + b * SS);
        int4 a = mp[tid * 2], c = mp[tid * 2 + 1];
        const short NEG = f2bf(-1e30f);
        s16x8 mo;
        mo[0] = a.x ? (short)0 : NEG; mo[1] = a.y ? (short)0 : NEG;
        mo[2] = a.z ? (short)0 : NEG; mo[3] = a.w ? (short)0 : NEG;
        mo[4] = c.x ? (short)0 : NEG; mo[5] = c.y ? (short)0 : NEG;
        mo[6] = c.z ? (short)0 : NEG; mo[7] = c.w ? (short)0 : NEG;
        *(s16x8*)&lsM[tid * 8] = mo;
    }

    // issue tile (kv0) K/V global->LDS DMA into buffer buf: 4 GLL per wave
    auto issue = [&](int kv0, int buf) {
#pragma unroll
        for (int jj = 0; jj < 2; ++jj) {
            int row = w * 16 + jj * 8 + grow;                  // key row
            GLL(Kb + baseQK + (size_t)(kv0 + row) * HDD + gcol,
                &lsK[buf][(w * 2 + jj) * 512]);
        }
#pragma unroll
        for (int jj = 0; jj < 2; ++jj) {
            int row = w * 16 + jj * 8 + grow;                  // hd row
            GLL(Vb + baseV + (size_t)row * SS + kv0 + gcol,
                &lsV[buf][(w * 2 + jj) * 512]);
        }
    };

    for (int t = 0; t < 2; ++t) {
        const int qb = t ? bx : (15 - bx);  // heavy q-tile first
        const int q0 = qb * 128;
        const int qw0 = q0 + w * 32;        // this wave's first q-row

        s16x8 aq[2][2];
#pragma unroll
        for (int s = 0; s < 2; ++s)
#pragma unroll
            for (int ks = 0; ks < 2; ++ks)
                aq[s][ks] = *(const s16x8*)(Q + baseQK +
                    (size_t)(qw0 + s * 16 + l15) * HDD + ks * 32 + quad * 8);

        float m_r[2], l_r[2];
        f32x4 o_acc[2][4] = {};
#pragma unroll
        for (int s = 0; s < 2; ++s) { m_r[s] = -1e30f; l_r[s] = 0.f; }

        const int ntiles = 2 * qb + 2;      // 64-key tiles; last two are diagonal

        lds_barrier();                      // prev t's reads done / mask visible
        issue(0, 0);

        auto tile = [&](auto CC, int kv0, int buf, int kvn) {
            constexpr bool CAUS = decltype(CC)::value;

            lds_barrier();                  // A: all waves done reading buf^1
            if (kvn >= 0) issue(kvn, buf ^ 1);

            // mask additive: 4 consecutive k per nt (8B broadcast-friendly read)
            float madd[4][4];
#pragma unroll
            for (int nt = 0; nt < 4; ++nt) {
                uint2 mw4 = *(const uint2*)&lsM[kv0 + nt * 16 + quad * 4];
                madd[nt][0] = bf2f((short)(mw4.x & 0xffff));
                madd[nt][1] = bf2f((short)(mw4.x >> 16));
                madd[nt][2] = bf2f((short)(mw4.y & 0xffff));
                madd[nt][3] = bf2f((short)(mw4.y >> 16));
            }

            if (kvn >= 0) asm volatile("s_waitcnt vmcnt(4)" ::: "memory");
            else          asm volatile("s_waitcnt vmcnt(0)" ::: "memory");
            __builtin_amdgcn_sched_barrier(0);
            __builtin_amdgcn_s_barrier();   // B: all waves' GLLs for buf landed
            __builtin_amdgcn_sched_barrier(0);

            // S^T = K Q^T : D[key][q]; lane holds q=l15, key=kv0+nt*16+quad*4+r
            f32x4 sv[2][4];
#pragma unroll
            for (int s = 0; s < 2; ++s)
#pragma unroll
                for (int nt = 0; nt < 4; ++nt) sv[s][nt] = f32x4{};
#pragma unroll
            for (int ks = 0; ks < 2; ++ks)
#pragma unroll
                for (int nt = 0; nt < 4; ++nt) {
                    s16x8 kf = *(const s16x8*)&lsK[buf][(nt * 16 + l15) * 64 +
                                                       (((ks * 4 + quad) ^ l7) * 8)];
#pragma unroll
                    for (int s = 0; s < 2; ++s)
                        sv[s][nt] = __builtin_amdgcn_mfma_f32_16x16x32_bf16(
                                        kf, aq[s][ks], sv[s][nt], 0, 0, 0);
                }

            // scale + key-mask + causal (k now lane-indexed, q = l15)
#pragma unroll
            for (int s = 0; s < 2; ++s) {
                const int qg = qw0 + s * 16 + l15;
#pragma unroll
                for (int nt = 0; nt < 4; ++nt) {
                    const int kg0 = kv0 + nt * 16 + quad * 4;
#pragma unroll
                    for (int r = 0; r < 4; ++r) {
                        float scv = sv[s][nt][r] * SC + madd[nt][r];
                        if (CAUS && kg0 + r > qg) scv = -1e30f;
                        sv[s][nt][r] = scv;
                    }
                }
            }

            // row max over keys: 16 in-lane + cross-quad (2 shfl)
            float rm[2];
#pragma unroll
            for (int s = 0; s < 2; ++s) {
                float v = fmaxf(fmaxf(fmaxf(sv[s][0][0], sv[s][0][1]),
                                      fmaxf(sv[s][0][2], sv[s][0][3])),
                                fmaxf(fmaxf(sv[s][1][0], sv[s][1][1]),
                                      fmaxf(sv[s][1][2], sv[s][1][3])));
                float v2 = fmaxf(fmaxf(fmaxf(sv[s][2][0], sv[s][2][1]),
                                       fmaxf(sv[s][2][2], sv[s][2][3])),
                                 fmaxf(fmaxf(sv[s][3][0], sv[s][3][1]),
                                       fmaxf(sv[s][3][2], sv[s][3][3])));
                v = fmaxf(v, v2);
                v = fmaxf(v, __shfl_xor(v, 16));
                v = fmaxf(v, __shfl_xor(v, 32));
                rm[s] = v;
            }
            // T13 defer-max: rescale only when some row's max grew > 8 (log2 domain)
            float need = fmaxf(rm[0] - m_r[0], rm[1] - m_r[1]);
            if (!__all(need <= 8.0f)) {
#pragma unroll
                for (int s = 0; s < 2; ++s) {
                    float nm = fmaxf(m_r[s], rm[s]);
                    float al = __builtin_amdgcn_exp2f(m_r[s] - nm);
                    m_r[s] = nm;
                    l_r[s] *= al;
#pragma unroll
                    for (int r = 0; r < 4; ++r) {
                        float alq = __shfl(al, (quad << 2) + r + (lane & 48));
#pragma unroll
                        for (int ht = 0; ht < 4; ++ht)
                            o_acc[s][ht][r] *= alq;
                    }
                }
            }
            // P = exp2(S - m); per-lane partial l (cross-quad sum at epilogue)
#pragma unroll
            for (int s = 0; s < 2; ++s) {
                float rs = 0.f;
#pragma unroll
                for (int nt = 0; nt < 4; ++nt)
#pragma unroll
                    for (int r = 0; r < 4; ++r) {
                        float p = __builtin_amdgcn_exp2f(sv[s][nt][r] - m_r[s]);
                        sv[s][nt][r] = p;
                        rs += p;
                    }
                l_r[s] += rs;
            }

            // P -> wave-private buffer: 4 consecutive k per lane = 1 ds_write_b64
            // granule g8=(nt*2+(quad>>1))^(l15&7), half quad&1  == reader's (k2*4+quad)^l7
            short* lsPw = lsP[w];
#pragma unroll
            for (int s = 0; s < 2; ++s)
#pragma unroll
                for (int nt = 0; nt < 4; ++nt) {
                    uint2 pw;
                    pw.x = pk2(sv[s][nt][0], sv[s][nt][1]);
                    pw.y = pk2(sv[s][nt][2], sv[s][nt][3]);
                    int row = s * 16 + l15;
                    int g8 = (nt * 2 + (quad >> 1)) ^ l7;
                    *(uint2*)&lsPw[row * 64 + (g8 << 3) + ((quad & 1) << 2)] = pw;
                }
            asm volatile("s_waitcnt lgkmcnt(0)" ::: "memory");
            __builtin_amdgcn_sched_barrier(0);

            // O += P V (ap read identical to round 8; V read unchanged)
            s16x8 ap[2][2];
#pragma unroll
            for (int s = 0; s < 2; ++s)
#pragma unroll
                for (int k2 = 0; k2 < 2; ++k2)
                    ap[s][k2] = *(const s16x8*)&lsPw[(s * 16 + l15) * 64 +
                                                     (((k2 * 4 + quad) ^ l7) << 3)];
#pragma unroll
            for (int ht = 0; ht < 4; ++ht)
#pragma unroll
                for (int k2 = 0; k2 < 2; ++k2) {
                    s16x8 vf = *(const s16x8*)&lsV[buf][(ht * 16 + l15) * 64 +
                                                        (((k2 * 4 + quad) ^ l7) * 8)];
#pragma unroll
                    for (int s = 0; s < 2; ++s)
                        o_acc[s][ht] = __builtin_amdgcn_mfma_f32_16x16x32_bf16(
                                           ap[s][k2], vf, o_acc[s][ht], 0, 0, 0);
                }
        };

        for (int kt = 0; kt < ntiles; ++kt) {
            const int kvn = (kt + 1 < ntiles) ? (kt + 1) * 64 : -1;
            if (kt >= 2 * qb) tile(std::true_type{},  kt * 64, kt & 1, kvn);
            else              tile(std::false_type{}, kt * 64, kt & 1, kvn);
        }

        // epilogue: sum l across quads, redistribute to o_acc rows, write O
        const int hcol = (bh & 15) * HDD;
#pragma unroll
        for (int s = 0; s < 2; ++s) {
            float ls = l_r[s];
            ls += __shfl_xor(ls, 16);
            ls += __shfl_xor(ls, 32);      // full row-sum for q = l15
#pragma unroll
            for (int r = 0; r < 4; ++r) {
                float lq = __shfl(ls, (quad << 2) + r + (lane & 48));
                float inv = 1.0f / lq;
                int srow = qw0 + s * 16 + quad * 4 + r;
                size_t base = ((size_t)b * SS + srow) * DD + hcol;
#pragma unroll
                for (int ht = 0; ht < 4; ++ht)
                    O[base + ht * 16 + l15] = f2bf(o_acc[s][ht][r] * inv);
            }
        }
    }
}

// ---------------- launch ----------------
extern "C" void kernel_launch(void* const* d_in, const int* in_sizes, int n_in,
                              void* d_out, int out_size, void* d_ws, size_t ws_size,
                              hipStream_t stream) {
    const float* x     = (const float*)d_in[0];
    const int*   mask  = (const int*)d_in[1];
    const float* qkv_w = (const float*)d_in[2];
    const float* qkv_b = (const float*)d_in[3];
    const float* out_w = (const float*)d_in[4];
    const float* out_b = (const float*)d_in[5];
    float* out = (float*)d_out;

    const size_t M1 = (size_t)BB * SS;       // 8192
    short* ws  = (short*)d_ws;
    short* xb  = ws;
    short* qwb = xb  + M1 * DD;
    short* owb = qwb + (size_t)3 * DD * DD;
    short* Qb  = owb + (size_t)DD * DD;
    short* Kb  = Qb  + M1 * DD;
    short* Vb  = Kb  + M1 * DD;
    short* Ob  = Vb  + M1 * DD;

    cvt_kernel<<<(int)(M1 * DD / 8 / 256), 256, 0, stream>>>(x, xb, (int)(M1 * DD));
    cvt_kernel<<<3 * DD * DD / 8 / 256, 256, 0, stream>>>(qkv_w, qwb, 3 * DD * DD);
    cvt_kernel<<<DD * DD / 8 / 256, 256, 0, stream>>>(out_w, owb, DD * DD);

    // qkv: M=8192, N=3072 -> 64 x 24 = 1536 blocks (2/CU x 3 exact rounds)
    gemm128<1><<<1536, 256, 0, stream>>>(xb, qwb, qkv_b, nullptr,
                                         Qb, Kb, Vb, 8192, 3072, 1024, 24);
    attn_kernel<<<dim3(8, BB * HH), 256, 0, stream>>>(Qb, Kb, Vb, mask, Ob);
    // out: M=8192, N=1024 -> 64 x 8 = 512 blocks (2/CU x 1 round)
    gemm128<0><<<512, 256, 0, stream>>>(Ob, owb, out_b, out,
                                        nullptr, nullptr, nullptr, 8192, 1024, 1024, 8);
}